// Round 9
// baseline (4814.989 us; speedup 1.0000x reference)
//
#include <hip/hip_runtime.h>

#define NB 32
#define NT 1024
#define NH 512
#define NE 256
#define NV0 2048
#define NV1 512
#define G3H 1536
#define NPG 30          // nodes per group
#define NCHUNK 32       // hh chunks (16 hh x 3 gates each)
#define NSLOT 8         // blocks per chunk

typedef __attribute__((ext_vector_type(8))) short bf16x8;
typedef __attribute__((ext_vector_type(4))) float f32x4;
typedef unsigned short u16;
typedef unsigned int u32;
typedef unsigned long long u64;

__device__ __forceinline__ u16 bf16_hi(float x) {
  unsigned u = __float_as_uint(x);
  unsigned r = (u + 0x7FFF + ((u >> 16) & 1)) >> 16;
  return (u16)r;
}
__device__ __forceinline__ float bf16_f(u16 h) {
  return __uint_as_float(((unsigned)h) << 16);
}
__device__ __forceinline__ u32 pack_hl(float v) {
  u16 hi = bf16_hi(v);
  u16 lo = bf16_hi(v - bf16_f(hi));
  return (u32)hi | ((u32)lo << 16);
}
__device__ __forceinline__ float unpack_hl(u32 w) {
  return bf16_f((u16)w) + bf16_f((u16)(w >> 16));
}

// ---------------- prep ----------------

// gdone[0] preset (initial states "always ready"); grpnode row 0 -> group 0
__global__ void k_init(const float* __restrict__ hidden, u32* __restrict__ bufp,
                       int* __restrict__ gdone, int* __restrict__ grpnode) {
  int i = blockIdx.x * blockDim.x + threadIdx.x;
  if (i < NB * NH) bufp[i] = pack_hl(hidden[i]);
  if (i < 4096) gdone[i] = (i == 0) ? 64 : 0;
  if (i < NB) grpnode[i] = 0;
}

__global__ void k_transpose(const float* __restrict__ in, float* __restrict__ out) {
  __shared__ float tile[32][33];
  int bx = blockIdx.x, by = blockIdx.y;
  int x = threadIdx.x, y = threadIdx.y;
  #pragma unroll
  for (int j = 0; j < 4; ++j)
    tile[y + j * 8][x] = in[(by * 32 + y + j * 8) * 512 + bx * 32 + x];
  __syncthreads();
  #pragma unroll
  for (int j = 0; j < 4; ++j)
    out[(bx * 32 + y + j * 8) * 1536 + by * 32 + x] = tile[x][y + j * 8];
}

__global__ __launch_bounds__(256) void k_proj(const float* __restrict__ emb0,
                                              const float* __restrict__ emb1,
                                              const float* __restrict__ Wt_ih,
                                              float* __restrict__ proj0,
                                              float* __restrict__ proj1) {
  __shared__ float a[8][NE];
  int g0 = blockIdx.x * 8;
  int tid = threadIdx.x;
  for (int i = tid; i < 8 * NE; i += 256) {
    int v = g0 + (i >> 8);
    int k = i & 255;
    a[i >> 8][k] = (v < NV0) ? emb0[v * NE + k] : emb1[(v - NV0) * NE + k];
  }
  __syncthreads();
  bool is0 = (g0 < NV0);
  int koff = is0 ? 0 : NE;
  float acc[8][6];
  #pragma unroll
  for (int v = 0; v < 8; ++v)
    #pragma unroll
    for (int j = 0; j < 6; ++j) acc[v][j] = 0.f;
  for (int k = 0; k < NE; ++k) {
    const float* wrow = Wt_ih + (size_t)(k + koff) * G3H;
    float w[6];
    #pragma unroll
    for (int j = 0; j < 6; ++j) w[j] = wrow[tid + j * 256];
    #pragma unroll
    for (int v = 0; v < 8; ++v) {
      float av = a[v][k];
      #pragma unroll
      for (int j = 0; j < 6; ++j) acc[v][j] += av * w[j];
    }
  }
  float* outp = is0 ? (proj0 + (size_t)g0 * G3H) : (proj1 + (size_t)(g0 - NV0) * G3H);
  for (int v = 0; v < 8; ++v)
    for (int j = 0; j < 6; ++j)
      outp[(size_t)v * G3H + tid + j * 256] = acc[v][j];
}

// W_hh split: tile tt = (hh>>4)*3 + g ; chunk c's slab = tiles [3c, 3c+3), contiguous
__global__ void k_wsplit(const float* __restrict__ W_hh, u16* __restrict__ Wfh,
                         u16* __restrict__ Wfl) {
  int idx = blockIdx.x * blockDim.x + threadIdx.x;
  if (idx >= G3H * NH) return;
  int row = idx >> 9, k = idx & 511;
  int g = row >> 9, hh = row & 511;
  int tt = (hh >> 4) * 3 + g;
  size_t phys = ((size_t)tt * 64 + (k >> 3)) * 128 + (hh & 15) * 8 + (k & 7);
  float v = W_hh[idx];
  u16 hi = bf16_hi(v);
  Wfh[phys] = hi;
  Wfl[phys] = bf16_hi(v - bf16_f(hi));
}

__global__ void k_wsplit_dec(const float* __restrict__ W, u16* __restrict__ Wh,
                             u16* __restrict__ Wl, int R) {
  int idx = blockIdx.x * blockDim.x + threadIdx.x;
  if (idx >= R * 512) return;
  int row = idx >> 9, k = idx & 511;
  size_t phys = ((size_t)(row >> 4) * 64 + (k >> 3)) * 128 + (row & 15) * 8 + (k & 7);
  float v = W[idx];
  u16 hi = bf16_hi(v);
  Wh[phys] = hi;
  Wl[phys] = bf16_hi(v - bf16_f(hi));
}

__global__ void k_levels(const int* __restrict__ cond, int* __restrict__ plv,
                         int* __restrict__ cntb) {
  __shared__ int c_lds[NT];
  __shared__ int lvl[NT + 1];
  __shared__ int cnt[NT + 1];
  int b = blockIdx.x, tid = threadIdx.x;
  for (int i = tid; i < NT; i += 256) c_lds[i] = cond[b * NT + i];
  for (int i = tid; i <= NT; i += 256) cnt[i] = 0;
  __syncthreads();
  if (tid == 0) {
    lvl[0] = 0;
    for (int t = 0; t < NT; ++t) {
      lvl[t + 1] = lvl[c_lds[t]] + 1;
      cnt[lvl[t + 1] - 1]++;
    }
  }
  __syncthreads();
  for (int t = tid; t < NT; t += 256) plv[b * NT + t] = lvl[t + 1] - 1;
  for (int p = tid; p <= NT; p += 256) cntb[p * NB + b] = cnt[p];
}

// scan + group list (sorted by level): desc = (start<<6)|nb, nb<=NPG.
// Also emit g_itemoff[p] (group index base per level) for grpnode computation.
__global__ void k_scan(const int* __restrict__ cntb, int* __restrict__ level_offset,
                       int* __restrict__ startpb, int* __restrict__ items,
                       int* __restrict__ g_itemoff, int* __restrict__ meta) {
  __shared__ int rowsum[NT + 1];
  __shared__ int itemoff[NT + 1];
  int tid = threadIdx.x;
  for (int p = tid; p <= NT; p += 1024) {
    int s = 0;
    for (int b = 0; b < NB; ++b) s += cntb[p * NB + b];
    rowsum[p] = s;
  }
  __syncthreads();
  if (tid == 0) {
    int off = 0, io = 0;
    for (int p = 0; p <= NT; ++p) {
      level_offset[p] = off;
      itemoff[p] = io;
      off += rowsum[p];
      io += (rowsum[p] + NPG - 1) / NPG;
    }
    meta[3] = io;   // total groups
  }
  __syncthreads();
  for (int p = tid; p <= NT; p += 1024) {
    g_itemoff[p] = itemoff[p];
    int n = rowsum[p], base = level_offset[p], io = itemoff[p];
    for (int g0 = 0; g0 < n; g0 += NPG) {
      int nb = n - g0; if (nb > NPG) nb = NPG;
      items[io++] = ((base + g0) << 6) | nb;
    }
  }
  __syncthreads();
  for (int p = tid; p <= NT; p += 1024) {
    int off = level_offset[p];
    for (int b = 0; b < NB; ++b) {
      startpb[p * NB + b] = off;
      off += cntb[p * NB + b];
    }
  }
}

// scatter + per-node group id (grpnode[(t+1)*NB+b] = 1 + group index of node)
__global__ void k_scatter(const int* __restrict__ plv, const int* __restrict__ startpb,
                          const int* __restrict__ level_offset,
                          const int* __restrict__ g_itemoff,
                          int* __restrict__ node_list, int* __restrict__ grpnode) {
  __shared__ int cur[NT + 1];
  __shared__ int lo_s[NT + 1];
  __shared__ int io_s[NT + 1];
  int b = blockIdx.x, tid = threadIdx.x;
  for (int p = tid; p <= NT; p += 256) {
    cur[p] = startpb[p * NB + b];
    lo_s[p] = level_offset[p];
    io_s[p] = g_itemoff[p];
  }
  __syncthreads();
  if (tid == 0) {
    for (int t = 0; t < NT; ++t) {
      int p = plv[b * NT + t];
      int pos = cur[p]++;
      node_list[pos] = (b << 16) | t;
      grpnode[(t + 1) * NB + b] = 1 + io_s[p] + (pos - lo_s[p]) / NPG;
    }
  }
}

// ---------------- recurrence: W-resident specialists, lean handoff ----------------
// 32 chunks x 8 slots, static item assignment (it = slot, slot+8, ...).
// Group flags: gdone[1+it] counts 64 (32 chunks x 2 MFMA waves). Producer waves
// publish independently after a PER-WAVE vmcnt(0) drain (rows 14/15 duplicated,
// bitwise-identical -> concurrent identical stores benign). Consumers poll
// parent-GROUP flags (grpnode), ~2 distinct addresses per item.

__global__ __launch_bounds__(256, 1) void rnn_steps(
    const int* __restrict__ items, const int* __restrict__ meta,
    const int* __restrict__ node_list, const int* __restrict__ grpnode,
    const int* __restrict__ cond, const int* __restrict__ tok0,
    const int* __restrict__ tok1,
    const u16* __restrict__ Wfh, const u16* __restrict__ Wfl,
    const float* __restrict__ proj0, const float* __restrict__ proj1,
    const float* __restrict__ b_ih, const float* __restrict__ b_hh,
    u32* __restrict__ bufp, int* gdone) {
  __shared__ u16 w_hi[3 * 8192];                 // 49,152 B
  __shared__ u16 w_lo[3 * 8192];                 // 49,152 B
  __shared__ unsigned char hds_h[NPG * 1024];    // 30,720 B
  __shared__ unsigned char hds_l[NPG * 1024];    // 30,720 B
  __shared__ int s_tb[NPG], s_pg[NPG], s_par[NPG], s_k0[NPG], s_k1[NPG];
  int tid = threadIdx.x;
  int w = tid >> 6, lane = tid & 63, q = lane >> 4, m = lane & 15;
  int c = blockIdx.x & (NCHUNK - 1);
  int slot = blockIdx.x >> 5;
  int total = meta[3];

  // ---- preload this chunk's W slab into LDS (once) ----
  {
    const uint4* sh = (const uint4*)(Wfh + (size_t)c * 3 * 8192);
    const uint4* sl = (const uint4*)(Wfl + (size_t)c * 3 * 8192);
    uint4* dh = (uint4*)w_hi;
    uint4* dl = (uint4*)w_lo;
    for (int i = tid; i < 3072; i += 256) { dh[i] = sh[i]; dl[i] = sl[i]; }
  }

  for (int it = slot; it < total; it += NSLOT) {
    __syncthreads();   // protect LDS from previous iteration (and W preload)
    int desc = items[it];
    int start = desc >> 6, nb = desc & 63;
    if (tid < NPG) {
      int b = 0, t = -1, par = 0, q0 = 0, q1 = 0, pg = 0;
      if (tid < nb) {
        int pk = node_list[start + tid];
        b = pk >> 16; t = pk & 0xFFFF;
        par = cond[b * NT + t];
        q0 = tok0[b * NT + t];
        q1 = tok1[b * NT + t];
        pg = grpnode[par * NB + b];
      }
      s_tb[tid] = (t + 1) * NB + b;
      s_par[tid] = par * NB + b;
      s_k0[tid] = q0; s_k1[tid] = q1;
      s_pg[tid] = pg;
    }
    __syncthreads();
    // ---- gi gather (independent of parents): seeds accumulators ----
    int hh = c * 16 + m;
    int nodebase = (w == 0) ? 0 : 14;   // only waves 0,1 compute
    f32x4 aR, aZ, aN;
    float gin[4];
    if (w < 2) {
      float bir = b_ih[hh] + b_hh[hh];
      float biz = b_ih[NH + hh] + b_hh[NH + hh];
      float bin = b_ih[2 * NH + hh];
      float bhn = b_hh[2 * NH + hh];
      #pragma unroll
      for (int i = 0; i < 4; ++i) {
        int node = nodebase + q * 4 + i;
        const float* p0 = proj0 + (size_t)s_k0[node] * G3H;
        const float* p1 = proj1 + (size_t)s_k1[node] * G3H;
        aR[i] = p0[hh] + p1[hh] + bir;
        aZ[i] = p0[NH + hh] + p1[NH + hh] + biz;
        gin[i] = p0[2 * NH + hh] + p1[2 * NH + hh] + bin;
        aN[i] = bhn;
      }
    }
    // ---- dependency poll: parent-GROUP flags (few distinct addresses) ----
    if (tid < NPG) {
      const int* f = gdone + s_pg[tid];
      while (__hip_atomic_load(f, __ATOMIC_RELAXED, __HIP_MEMORY_SCOPE_AGENT) < 64)
        __builtin_amdgcn_s_sleep(1);
    }
    __syncthreads();
    asm volatile("" ::: "memory");
    // ---- stage NPG parent states into split hi/lo LDS (swizzled) ----
    for (int idx = tid; idx < NPG * 16; idx += 256) {
      int r = idx >> 4, seg = idx & 15;
      size_t src = (size_t)s_par[r] * NH + seg * 32;
      u64 dv[16];
      #pragma unroll
      for (int k2 = 0; k2 < 16; ++k2)
        dv[k2] = __hip_atomic_load((const u64*)&bufp[src + k2 * 2],
                                   __ATOMIC_RELAXED, __HIP_MEMORY_SCOPE_AGENT);
      int swz = (r & 7) << 4;
      #pragma unroll
      for (int k2 = 0; k2 < 16; ++k2) {
        u32 e0 = (u32)dv[k2], e1 = (u32)(dv[k2] >> 32);
        int wi = seg * 32 + k2 * 2;
        int a = r * 1024 + (((wi >> 3) * 16) ^ swz) + ((2 * wi) & 15);
        *(u32*)(hds_h + a) = (e0 & 0xFFFFu) | (e1 << 16);
        *(u32*)(hds_l + a) = (e0 >> 16) | (e1 & 0xFFFF0000u);
      }
    }
    __syncthreads();
    if (w < 2) {
      // ---- MFMA: all operands from LDS; 3 gates, 16 nodes/wave, K=512, 3-split ----
      int r = nodebase + m;
      int arowbase = r * 1024;
      int aswz = (r & 7) << 4;
      #pragma unroll 4
      for (int s = 0; s < 16; ++s) {
        int ab = arowbase + (((s * 64) + (q * 16)) ^ aswz);
        bf16x8 ah = *(const bf16x8*)(hds_h + ab);
        bf16x8 al = *(const bf16x8*)(hds_l + ab);
        int koff = (s * 4 + q) * 128 + m * 8;
        bf16x8 bh0 = *(const bf16x8*)(w_hi + koff);
        bf16x8 bl0 = *(const bf16x8*)(w_lo + koff);
        bf16x8 bh1 = *(const bf16x8*)(w_hi + 8192 + koff);
        bf16x8 bl1 = *(const bf16x8*)(w_lo + 8192 + koff);
        bf16x8 bh2 = *(const bf16x8*)(w_hi + 16384 + koff);
        bf16x8 bl2 = *(const bf16x8*)(w_lo + 16384 + koff);
        aR = __builtin_amdgcn_mfma_f32_16x16x32_bf16(ah, bh0, aR, 0, 0, 0);
        aR = __builtin_amdgcn_mfma_f32_16x16x32_bf16(ah, bl0, aR, 0, 0, 0);
        aR = __builtin_amdgcn_mfma_f32_16x16x32_bf16(al, bh0, aR, 0, 0, 0);
        aZ = __builtin_amdgcn_mfma_f32_16x16x32_bf16(ah, bh1, aZ, 0, 0, 0);
        aZ = __builtin_amdgcn_mfma_f32_16x16x32_bf16(ah, bl1, aZ, 0, 0, 0);
        aZ = __builtin_amdgcn_mfma_f32_16x16x32_bf16(al, bh1, aZ, 0, 0, 0);
        aN = __builtin_amdgcn_mfma_f32_16x16x32_bf16(ah, bh2, aN, 0, 0, 0);
        aN = __builtin_amdgcn_mfma_f32_16x16x32_bf16(ah, bl2, aN, 0, 0, 0);
        aN = __builtin_amdgcn_mfma_f32_16x16x32_bf16(al, bh2, aN, 0, 0, 0);
      }
      // ---- in-register GRU epilogue; packed u32 agent-atomic state stores ----
      #pragma unroll
      for (int i = 0; i < 4; ++i) {
        int node = nodebase + q * 4 + i;
        if (node < nb) {
          float rg = 1.f / (1.f + __expf(-aR[i]));
          float zg = 1.f / (1.f + __expf(-aZ[i]));
          float nn = 1.f - 2.f / (1.f + __expf(2.f * (gin[i] + rg * aN[i])));
          int hofs = node * 1024 + ((hh * 2) ^ ((node & 7) << 4));
          float hp = bf16_f(*(const u16*)(hds_h + hofs)) + bf16_f(*(const u16*)(hds_l + hofs));
          float hn = (1.f - zg) * nn + zg * hp;
          __hip_atomic_store(&bufp[(size_t)s_tb[node] * NH + hh], pack_hl(hn),
                             __ATOMIC_RELAXED, __HIP_MEMORY_SCOPE_AGENT);
        }
      }
      // per-WAVE drain (vmcnt is a wave-level counter), then publish (release)
      asm volatile("s_waitcnt vmcnt(0)" ::: "memory");
      if (lane == 0)
        __hip_atomic_fetch_add(&gdone[1 + it], 1, __ATOMIC_RELEASE,
                               __HIP_MEMORY_SCOPE_AGENT);
    }
  }
}

// ---------------- decode GEMM: MFMA bf16 3-split, packed-state input ----------------

__global__ __launch_bounds__(256) void k_dec(const u32* __restrict__ bufp,
                                             const u16* __restrict__ Wh,
                                             const u16* __restrict__ Wl,
                                             const float* __restrict__ bias,
                                             float* __restrict__ out, int N) {
  __shared__ u16 Ah[64 * 128];
  __shared__ u16 Al[64 * 128];
  int tid = threadIdx.x;
  int w = tid >> 6, lane = tid & 63, q = lane >> 4, m = lane & 15;
  int n0 = blockIdx.x * 64, m0 = blockIdx.y * 64;
  f32x4 acc[4];
  #pragma unroll
  for (int n = 0; n < 4; ++n) acc[n] = (f32x4){0.f, 0.f, 0.f, 0.f};
  for (int c = 0; c < 4; ++c) {
    __syncthreads();
    #pragma unroll
    for (int r = 0; r < 8; ++r) {
      int idx = r * 256 + tid;           // 2048 16B-loads = 64 rows x 32 segs
      int row = idx >> 5, seg = idx & 31;
      int gm = m0 + row;
      size_t bufrow = (size_t)((gm & (NT - 1)) + 1) * NB + (gm >> 10);
      uint4 vv = *(const uint4*)(bufp + bufrow * NH + c * 128 + seg * 4);
      int a = row * 256 + (((seg >> 1) * 16) ^ ((row & 7) << 4)) + (seg & 1) * 8;
      uint2 hp, lp;
      hp.x = (vv.x & 0xFFFFu) | (vv.y << 16);
      hp.y = (vv.z & 0xFFFFu) | (vv.w << 16);
      lp.x = (vv.x >> 16) | (vv.y & 0xFFFF0000u);
      lp.y = (vv.z >> 16) | (vv.w & 0xFFFF0000u);
      *(uint2*)((unsigned char*)Ah + a) = hp;
      *(uint2*)((unsigned char*)Al + a) = lp;
    }
    __syncthreads();
    #pragma unroll
    for (int s = 0; s < 4; ++s) {
      int arow = w * 16 + m;
      int aoff = arow * 256 + (((s * 64) + (q * 16)) ^ ((arow & 7) << 4));
      bf16x8 ah = *(const bf16x8*)((unsigned char*)Ah + aoff);
      bf16x8 al = *(const bf16x8*)((unsigned char*)Al + aoff);
      #pragma unroll
      for (int n = 0; n < 4; ++n) {
        size_t b = ((size_t)(n0 / 16 + n) * 64 + (c * 16 + s * 4 + q)) * 128 + m * 8;
        bf16x8 bh = *(const bf16x8*)(Wh + b);
        bf16x8 bl = *(const bf16x8*)(Wl + b);
        acc[n] = __builtin_amdgcn_mfma_f32_16x16x32_bf16(ah, bh, acc[n], 0, 0, 0);
        acc[n] = __builtin_amdgcn_mfma_f32_16x16x32_bf16(ah, bl, acc[n], 0, 0, 0);
        acc[n] = __builtin_amdgcn_mfma_f32_16x16x32_bf16(al, bh, acc[n], 0, 0, 0);
      }
    }
  }
  #pragma unroll
  for (int n = 0; n < 4; ++n) {
    int col = n0 + n * 16 + m;
    float bv = bias[col];
    #pragma unroll
    for (int i = 0; i < 4; ++i) {
      int mrow = m0 + w * 16 + q * 4 + i;
      out[(size_t)mrow * N + col] = acc[n][i] + bv;
    }
  }
}

__global__ void k_tail(const u32* __restrict__ bufp, float* __restrict__ out) {
  int i = blockIdx.x * blockDim.x + threadIdx.x;
  if (i < NB * NH) out[i] = unpack_hl(bufp[(size_t)NT * NB * NH + i]);
}

// ---------------- launch ----------------

extern "C" void kernel_launch(void* const* d_in, const int* in_sizes, int n_in,
                              void* d_out, int out_size, void* d_ws, size_t ws_size,
                              hipStream_t stream) {
  const int*   tokens0    = (const int*)d_in[0];
  const int*   tokens1    = (const int*)d_in[1];
  const int*   conditions = (const int*)d_in[2];
  const float* hidden     = (const float*)d_in[3];
  const float* emb0       = (const float*)d_in[4];
  const float* emb1       = (const float*)d_in[5];
  const float* W_ih       = (const float*)d_in[6];
  const float* W_hh       = (const float*)d_in[7];
  const float* b_ih       = (const float*)d_in[8];
  const float* b_hh       = (const float*)d_in[9];
  const float* dec0_W     = (const float*)d_in[10];
  const float* dec0_b     = (const float*)d_in[11];
  const float* dec1_W     = (const float*)d_in[12];
  const float* dec1_b     = (const float*)d_in[13];

  char* wsb = (char*)d_ws;
  float* proj0 = (float*)wsb;                      // 12,582,912 B
  float* proj1 = (float*)(wsb + 12582912);         //  3,145,728 B
  float* Wt_ih = (float*)(wsb + 15728640);         //  3,145,728 B (reused below)
  // grpnode/items/gdone/g_itemoff overlay Wt_ih's region: used AFTER k_proj
  int*   grpnode  = (int*)(wsb + 15728640);        // 32800 ints = 131,200 B
  int*   items    = (int*)(wsb + 15859840);        // <= 4096 ints
  int*   gdone    = (int*)(wsb + 15876224);        // 4096 ints
  int*   g_itemoff= (int*)(wsb + 15892608);        // 1025 ints
  u32*   bufp  = (u32*)(wsb + 18874368);           // 1025*32*512 u32 = 67,174,400 B
  u16*   Wfh   = (u16*)(wsb + 86048768);           //  1,572,864 B
  u16*   Wfl   = (u16*)(wsb + 87621632);           //  1,572,864 B
  u16*   d0Wh  = (u16*)(wsb + 89194496);           //  2,097,152 B
  u16*   d0Wl  = (u16*)(wsb + 91291648);           //  2,097,152 B
  u16*   d1Wh  = (u16*)(wsb + 93388800);           //    524,288 B
  u16*   d1Wl  = (u16*)(wsb + 93913088);           //    524,288 B
  int*   iws   = (int*)(wsb + 94437376);
  int* plv          = iws;                 // 32768
  int* cntb         = iws + 32768;         // 32800
  int* level_offset = iws + 65568;         // 1026
  int* startpb      = iws + 66594;         // 32800
  int* meta         = iws + 99394;         // 16 ([3]=total groups)
  int* node_list    = iws + 99410;         // 32768

  float* out0 = (float*)d_out;
  float* out1 = out0 + (size_t)NB * NT * NV0;
  float* outT = out1 + (size_t)NB * NT * NV1;

  // Wt_ih produced+consumed first; then its region is reused for dataflow state.
  k_transpose<<<dim3(16, 48), dim3(32, 8), 0, stream>>>(W_ih, Wt_ih);
  k_proj<<<320, 256, 0, stream>>>(emb0, emb1, Wt_ih, proj0, proj1);
  k_init<<<130, 256, 0, stream>>>(hidden, bufp, gdone, grpnode);
  k_wsplit<<<3072, 256, 0, stream>>>(W_hh, Wfh, Wfl);
  k_wsplit_dec<<<4096, 256, 0, stream>>>(dec0_W, d0Wh, d0Wl, NV0);
  k_wsplit_dec<<<1024, 256, 0, stream>>>(dec1_W, d1Wh, d1Wl, NV1);
  k_levels<<<32, 256, 0, stream>>>(conditions, plv, cntb);
  k_scan<<<1, 1024, 0, stream>>>(cntb, level_offset, startpb, items, g_itemoff, meta);
  k_scatter<<<32, 256, 0, stream>>>(plv, startpb, level_offset, g_itemoff,
                                    node_list, grpnode);

  rnn_steps<<<256, 256, 0, stream>>>(items, meta, node_list, grpnode, conditions,
                                     tokens0, tokens1, Wfh, Wfl, proj0, proj1,
                                     b_ih, b_hh, bufp, gdone);

  k_dec<<<dim3(NV0 / 64, (NB * NT) / 64), 256, 0, stream>>>(bufp, d0Wh, d0Wl, dec0_b, out0, NV0);
  k_dec<<<dim3(NV1 / 64, (NB * NT) / 64), 256, 0, stream>>>(bufp, d1Wh, d1Wl, dec1_b, out1, NV1);
  k_tail<<<64, 256, 0, stream>>>(bufp, outT);
}

// Round 10
// 3215.238 us; speedup vs baseline: 1.4976x; 1.4976x over previous
//
#include <hip/hip_runtime.h>

#define NB 32
#define NT 1024
#define NH 512
#define NE 256
#define NV0 2048
#define NV1 512
#define G3H 1536
#define NCHUNK 16       // hh chunks (32 hh x 3 gates each)

typedef __attribute__((ext_vector_type(8))) short bf16x8;
typedef __attribute__((ext_vector_type(4))) float f32x4;
typedef unsigned short u16;
typedef unsigned int u32;
typedef unsigned long long u64;

__device__ __forceinline__ u16 bf16_hi(float x) {
  unsigned u = __float_as_uint(x);
  unsigned r = (u + 0x7FFF + ((u >> 16) & 1)) >> 16;
  return (u16)r;
}
__device__ __forceinline__ float bf16_f(u16 h) {
  return __uint_as_float(((unsigned)h) << 16);
}
__device__ __forceinline__ u32 pack_hl(float v) {
  u16 hi = bf16_hi(v);
  u16 lo = bf16_hi(v - bf16_f(hi));
  return (u32)hi | ((u32)lo << 16);
}
__device__ __forceinline__ float unpack_hl(u32 w) {
  return bf16_f((u16)w) + bf16_f((u16)(w >> 16));
}

// ---------------- prep ----------------

// gdone[b*1026 + f]: level-(f-1) completion counter for batch b; f=0 preset ready.
__global__ void k_init(const float* __restrict__ hidden, u32* __restrict__ bufp,
                       int* __restrict__ gdone) {
  int i = blockIdx.x * blockDim.x + threadIdx.x;
  if (i < NB * NH) bufp[i] = pack_hl(hidden[i]);
  if (i < NB * 1026) gdone[i] = ((i % 1026) == 0) ? NCHUNK : 0;
}

__global__ void k_transpose(const float* __restrict__ in, float* __restrict__ out) {
  __shared__ float tile[32][33];
  int bx = blockIdx.x, by = blockIdx.y;
  int x = threadIdx.x, y = threadIdx.y;
  #pragma unroll
  for (int j = 0; j < 4; ++j)
    tile[y + j * 8][x] = in[(by * 32 + y + j * 8) * 512 + bx * 32 + x];
  __syncthreads();
  #pragma unroll
  for (int j = 0; j < 4; ++j)
    out[(bx * 32 + y + j * 8) * 1536 + by * 32 + x] = tile[x][y + j * 8];
}

__global__ __launch_bounds__(256) void k_proj(const float* __restrict__ emb0,
                                              const float* __restrict__ emb1,
                                              const float* __restrict__ Wt_ih,
                                              float* __restrict__ proj0,
                                              float* __restrict__ proj1) {
  __shared__ float a[8][NE];
  int g0 = blockIdx.x * 8;
  int tid = threadIdx.x;
  for (int i = tid; i < 8 * NE; i += 256) {
    int v = g0 + (i >> 8);
    int k = i & 255;
    a[i >> 8][k] = (v < NV0) ? emb0[v * NE + k] : emb1[(v - NV0) * NE + k];
  }
  __syncthreads();
  bool is0 = (g0 < NV0);
  int koff = is0 ? 0 : NE;
  float acc[8][6];
  #pragma unroll
  for (int v = 0; v < 8; ++v)
    #pragma unroll
    for (int j = 0; j < 6; ++j) acc[v][j] = 0.f;
  for (int k = 0; k < NE; ++k) {
    const float* wrow = Wt_ih + (size_t)(k + koff) * G3H;
    float w[6];
    #pragma unroll
    for (int j = 0; j < 6; ++j) w[j] = wrow[tid + j * 256];
    #pragma unroll
    for (int v = 0; v < 8; ++v) {
      float av = a[v][k];
      #pragma unroll
      for (int j = 0; j < 6; ++j) acc[v][j] += av * w[j];
    }
  }
  float* outp = is0 ? (proj0 + (size_t)g0 * G3H) : (proj1 + (size_t)(g0 - NV0) * G3H);
  for (int v = 0; v < 8; ++v)
    for (int j = 0; j < 6; ++j)
      outp[(size_t)v * G3H + tid + j * 256] = acc[v][j];
}

// W_hh split: tile tt = (hh>>4)*3 + g  (32 hh16-blocks x 3 gates = 96 tiles of 16x512)
__global__ void k_wsplit(const float* __restrict__ W_hh, u16* __restrict__ Wfh,
                         u16* __restrict__ Wfl) {
  int idx = blockIdx.x * blockDim.x + threadIdx.x;
  if (idx >= G3H * NH) return;
  int row = idx >> 9, k = idx & 511;
  int g = row >> 9, hh = row & 511;
  int tt = (hh >> 4) * 3 + g;
  size_t phys = ((size_t)tt * 64 + (k >> 3)) * 128 + (hh & 15) * 8 + (k & 7);
  float v = W_hh[idx];
  u16 hi = bf16_hi(v);
  Wfh[phys] = hi;
  Wfl[phys] = bf16_hi(v - bf16_f(hi));
}

__global__ void k_wsplit_dec(const float* __restrict__ W, u16* __restrict__ Wh,
                             u16* __restrict__ Wl, int R) {
  int idx = blockIdx.x * blockDim.x + threadIdx.x;
  if (idx >= R * 512) return;
  int row = idx >> 9, k = idx & 511;
  size_t phys = ((size_t)(row >> 4) * 64 + (k >> 3)) * 128 + (row & 15) * 8 + (k & 7);
  float v = W[idx];
  u16 hi = bf16_hi(v);
  Wh[phys] = hi;
  Wl[phys] = bf16_hi(v - bf16_f(hi));
}

__global__ void k_levels(const int* __restrict__ cond, int* __restrict__ plv,
                         int* __restrict__ cntb) {
  __shared__ int c_lds[NT];
  __shared__ int lvl[NT + 1];
  __shared__ int cnt[NT + 1];
  int b = blockIdx.x, tid = threadIdx.x;
  for (int i = tid; i < NT; i += 256) c_lds[i] = cond[b * NT + i];
  for (int i = tid; i <= NT; i += 256) cnt[i] = 0;
  __syncthreads();
  if (tid == 0) {
    lvl[0] = 0;
    for (int t = 0; t < NT; ++t) {
      lvl[t + 1] = lvl[c_lds[t]] + 1;
      cnt[lvl[t + 1] - 1]++;
    }
  }
  __syncthreads();
  for (int t = tid; t < NT; t += 256) plv[b * NT + t] = lvl[t + 1] - 1;
  for (int p = tid; p <= NT; p += 256) cntb[p * NB + b] = cnt[p];
}

// per-batch item lists: items[b*1024 + j] = (p<<21)|(startIdx<<6)|nb, level-ordered.
// startIdx indexes node_list (per-batch region b*1024 + level prefix).
__global__ void k_scan(const int* __restrict__ cntb, int* __restrict__ items,
                       int* __restrict__ nitems, int* __restrict__ off_bp) {
  int b = threadIdx.x;
  if (b >= NB) return;
  int off = 0, io = 0;
  for (int p = 0; p <= NT; ++p) {
    int n = cntb[p * NB + b];
    off_bp[b * 1025 + p] = b * 1024 + off;
    for (int g0 = 0; g0 < n; g0 += 16) {
      int nb = n - g0; if (nb > 16) nb = 16;
      items[b * 1024 + io++] = (p << 21) | ((b * 1024 + off + g0) << 6) | nb;
    }
    off += n;
  }
  nitems[b] = io;
}

__global__ void k_scatter(const int* __restrict__ plv, const int* __restrict__ off_bp,
                          int* __restrict__ node_list) {
  __shared__ int cur[NT + 1];
  int b = blockIdx.x, tid = threadIdx.x;
  for (int p = tid; p <= NT; p += 256) cur[p] = off_bp[b * 1025 + p];
  __syncthreads();
  if (tid == 0) {
    for (int t = 0; t < NT; ++t) {
      int p = plv[b * NT + t];
      node_list[cur[p]++] = (b << 16) | t;
    }
  }
}

// ---------------- recurrence: per-batch level streams ----------------
// Grid = 16 chunks x 32 batches = 512 blocks of 128 threads (2 waves), all
// co-resident (2 blocks/CU). Block (c,b) walks batch b's levels in order.
// A node at level p has its single parent at EXACTLY level p-1 (same batch),
// so each level hop needs ONE flag: gdone[b][p] counted to NCHUNK by the 16
// chunk-blocks. No queues, no per-node flags, no cross-batch convoy.
// Race discipline (r7-proven): per-thread vmcnt(0) drain + barrier before the
// single RELEASE flag RMW; consumer relaxed-polls + compiler barrier; all
// state traffic is L3-coherent atomics.

__global__ __launch_bounds__(128, 8) void rnn_steps(
    const int* __restrict__ items, const int* __restrict__ nitems,
    const int* __restrict__ node_list, const int* __restrict__ cond,
    const int* __restrict__ tok0, const int* __restrict__ tok1,
    const u16* __restrict__ Wfh, const u16* __restrict__ Wfl,
    const float* __restrict__ proj0, const float* __restrict__ proj1,
    const float* __restrict__ b_ih, const float* __restrict__ b_hh,
    u32* __restrict__ bufp, int* gdone) {
  __shared__ unsigned char hds_h[16 * 1024];
  __shared__ unsigned char hds_l[16 * 1024];
  __shared__ int s_tb[16], s_par[16], s_k0[16], s_k1[16];
  int tid = threadIdx.x;
  int w = tid >> 6, lane = tid & 63, q = lane >> 4, m = lane & 15;
  int c = blockIdx.x & (NCHUNK - 1);
  int b = blockIdx.x >> 4;
  int nIt = nitems[b];
  const int* myItems = items + b * 1024;
  int* myGd = gdone + b * 1026;
  int prevp = -1;
  for (int j = 0; j < nIt; ++j) {
    __syncthreads();   // protect LDS from previous item
    int desc = myItems[j];
    int p = desc >> 21;
    int start = (desc >> 6) & 0x7FFF;
    int nb = desc & 63;
    if (tid < 16) {
      int bb = 0, t = -1, par = 0, q0 = 0, q1 = 0;
      if (tid < nb) {
        int pk = node_list[start + tid];
        bb = pk >> 16; t = pk & 0xFFFF;
        par = cond[bb * NT + t];
        q0 = tok0[bb * NT + t];
        q1 = tok1[bb * NT + t];
      }
      s_tb[tid] = (t + 1) * NB + bb;
      s_par[tid] = par * NB + bb;
      s_k0[tid] = q0; s_k1[tid] = q1;
    }
    __syncthreads();
    // ---- gi gather (independent of parents): seeds accumulators, pre-poll ----
    int hb = c * 2 + w;          // hh16-block owned by this wave
    int hh = hb * 16 + m;
    float bir = b_ih[hh] + b_hh[hh];
    float biz = b_ih[NH + hh] + b_hh[NH + hh];
    float bin = b_ih[2 * NH + hh];
    float bhn = b_hh[2 * NH + hh];
    f32x4 aR, aZ, aN;
    float gin[4];
    #pragma unroll
    for (int i = 0; i < 4; ++i) {
      int node = q * 4 + i;
      const float* p0 = proj0 + (size_t)s_k0[node] * G3H;
      const float* p1 = proj1 + (size_t)s_k1[node] * G3H;
      aR[i] = p0[hh] + p1[hh] + bir;
      aZ[i] = p0[NH + hh] + p1[NH + hh] + biz;
      gin[i] = p0[2 * NH + hh] + p1[2 * NH + hh] + bin;
      aN[i] = bhn;
    }
    // ---- dependency poll: ONE flag (parent level complete for this batch) ----
    if (p != prevp) {
      if (tid == 0) {
        while (__hip_atomic_load(&myGd[p], __ATOMIC_RELAXED, __HIP_MEMORY_SCOPE_AGENT)
               < NCHUNK)
          __builtin_amdgcn_s_sleep(1);
      }
      prevp = p;
    }
    __syncthreads();
    asm volatile("" ::: "memory");
    // ---- stage nb parent states into split hi/lo LDS (swizzled) ----
    for (int idx = tid; idx < nb * 16; idx += 128) {
      int r = idx >> 4, seg = idx & 15;
      size_t src = (size_t)s_par[r] * NH + seg * 32;
      u64 dv[16];
      #pragma unroll
      for (int k2 = 0; k2 < 16; ++k2)
        dv[k2] = __hip_atomic_load((const u64*)&bufp[src + k2 * 2],
                                   __ATOMIC_RELAXED, __HIP_MEMORY_SCOPE_AGENT);
      int swz = (r & 7) << 4;
      #pragma unroll
      for (int k2 = 0; k2 < 16; ++k2) {
        u32 e0 = (u32)dv[k2], e1 = (u32)(dv[k2] >> 32);
        int wi = seg * 32 + k2 * 2;
        int a = r * 1024 + (((wi >> 3) * 16) ^ swz) + ((2 * wi) & 15);
        *(u32*)(hds_h + a) = (e0 & 0xFFFFu) | (e1 << 16);
        *(u32*)(hds_l + a) = (e0 >> 16) | (e1 & 0xFFFF0000u);
      }
    }
    __syncthreads();
    // ---- MFMA: wave owns hb = c*2+w, 3 gates, 16 nodes, K=512, 3-split ----
    {
      const u16* wh = Wfh + (size_t)hb * 3 * 8192;
      const u16* wl = Wfl + (size_t)hb * 3 * 8192;
      #pragma unroll 4
      for (int s = 0; s < 16; ++s) {
        int ab = m * 1024 + (((s * 64) + (q * 16)) ^ ((m & 7) << 4));
        bf16x8 ah = *(const bf16x8*)(hds_h + ab);
        bf16x8 al = *(const bf16x8*)(hds_l + ab);
        int koff = (s * 4 + q) * 128 + m * 8;
        bf16x8 bh0 = *(const bf16x8*)(wh + koff);
        bf16x8 bl0 = *(const bf16x8*)(wl + koff);
        bf16x8 bh1 = *(const bf16x8*)(wh + 8192 + koff);
        bf16x8 bl1 = *(const bf16x8*)(wl + 8192 + koff);
        bf16x8 bh2 = *(const bf16x8*)(wh + 16384 + koff);
        bf16x8 bl2 = *(const bf16x8*)(wl + 16384 + koff);
        aR = __builtin_amdgcn_mfma_f32_16x16x32_bf16(ah, bh0, aR, 0, 0, 0);
        aR = __builtin_amdgcn_mfma_f32_16x16x32_bf16(ah, bl0, aR, 0, 0, 0);
        aR = __builtin_amdgcn_mfma_f32_16x16x32_bf16(al, bh0, aR, 0, 0, 0);
        aZ = __builtin_amdgcn_mfma_f32_16x16x32_bf16(ah, bh1, aZ, 0, 0, 0);
        aZ = __builtin_amdgcn_mfma_f32_16x16x32_bf16(ah, bl1, aZ, 0, 0, 0);
        aZ = __builtin_amdgcn_mfma_f32_16x16x32_bf16(al, bh1, aZ, 0, 0, 0);
        aN = __builtin_amdgcn_mfma_f32_16x16x32_bf16(ah, bh2, aN, 0, 0, 0);
        aN = __builtin_amdgcn_mfma_f32_16x16x32_bf16(ah, bl2, aN, 0, 0, 0);
        aN = __builtin_amdgcn_mfma_f32_16x16x32_bf16(al, bh2, aN, 0, 0, 0);
      }
      // ---- in-register GRU epilogue; packed u32 agent-atomic state stores ----
      #pragma unroll
      for (int i = 0; i < 4; ++i) {
        int node = q * 4 + i;
        if (node < nb) {
          float rg = 1.f / (1.f + __expf(-aR[i]));
          float zg = 1.f / (1.f + __expf(-aZ[i]));
          float nn = 1.f - 2.f / (1.f + __expf(2.f * (gin[i] + rg * aN[i])));
          int hofs = node * 1024 + ((hh * 2) ^ ((node & 7) << 4));
          float hp = bf16_f(*(const u16*)(hds_h + hofs)) + bf16_f(*(const u16*)(hds_l + hofs));
          float hn = (1.f - zg) * nn + zg * hp;
          __hip_atomic_store(&bufp[(size_t)s_tb[node] * NH + hh], pack_hl(hn),
                             __ATOMIC_RELAXED, __HIP_MEMORY_SCOPE_AGENT);
        }
      }
    }
    // ---- drain all threads' stores, then publish level completion (once) ----
    bool lastOfLevel = (j == nIt - 1) || ((myItems[j + 1] >> 21) != p);
    asm volatile("s_waitcnt vmcnt(0)" ::: "memory");
    __syncthreads();
    if (lastOfLevel && tid == 0)
      __hip_atomic_fetch_add(&myGd[p + 1], 1, __ATOMIC_RELEASE,
                             __HIP_MEMORY_SCOPE_AGENT);
  }
}

// ---------------- decode GEMM: MFMA bf16 3-split, packed-state input ----------------

__global__ __launch_bounds__(256) void k_dec(const u32* __restrict__ bufp,
                                             const u16* __restrict__ Wh,
                                             const u16* __restrict__ Wl,
                                             const float* __restrict__ bias,
                                             float* __restrict__ out, int N) {
  __shared__ u16 Ah[64 * 128];
  __shared__ u16 Al[64 * 128];
  int tid = threadIdx.x;
  int w = tid >> 6, lane = tid & 63, q = lane >> 4, m = lane & 15;
  int n0 = blockIdx.x * 64, m0 = blockIdx.y * 64;
  f32x4 acc[4];
  #pragma unroll
  for (int n = 0; n < 4; ++n) acc[n] = (f32x4){0.f, 0.f, 0.f, 0.f};
  for (int c = 0; c < 4; ++c) {
    __syncthreads();
    #pragma unroll
    for (int r = 0; r < 8; ++r) {
      int idx = r * 256 + tid;           // 2048 16B-loads = 64 rows x 32 segs
      int row = idx >> 5, seg = idx & 31;
      int gm = m0 + row;
      size_t bufrow = (size_t)((gm & (NT - 1)) + 1) * NB + (gm >> 10);
      uint4 vv = *(const uint4*)(bufp + bufrow * NH + c * 128 + seg * 4);
      int a = row * 256 + (((seg >> 1) * 16) ^ ((row & 7) << 4)) + (seg & 1) * 8;
      uint2 hp, lp;
      hp.x = (vv.x & 0xFFFFu) | (vv.y << 16);
      hp.y = (vv.z & 0xFFFFu) | (vv.w << 16);
      lp.x = (vv.x >> 16) | (vv.y & 0xFFFF0000u);
      lp.y = (vv.z >> 16) | (vv.w & 0xFFFF0000u);
      *(uint2*)((unsigned char*)Ah + a) = hp;
      *(uint2*)((unsigned char*)Al + a) = lp;
    }
    __syncthreads();
    #pragma unroll
    for (int s = 0; s < 4; ++s) {
      int arow = w * 16 + m;
      int aoff = arow * 256 + (((s * 64) + (q * 16)) ^ ((arow & 7) << 4));
      bf16x8 ah = *(const bf16x8*)((unsigned char*)Ah + aoff);
      bf16x8 al = *(const bf16x8*)((unsigned char*)Al + aoff);
      #pragma unroll
      for (int n = 0; n < 4; ++n) {
        size_t bo = ((size_t)(n0 / 16 + n) * 64 + (c * 16 + s * 4 + q)) * 128 + m * 8;
        bf16x8 bh = *(const bf16x8*)(Wh + bo);
        bf16x8 bl = *(const bf16x8*)(Wl + bo);
        acc[n] = __builtin_amdgcn_mfma_f32_16x16x32_bf16(ah, bh, acc[n], 0, 0, 0);
        acc[n] = __builtin_amdgcn_mfma_f32_16x16x32_bf16(ah, bl, acc[n], 0, 0, 0);
        acc[n] = __builtin_amdgcn_mfma_f32_16x16x32_bf16(al, bh, acc[n], 0, 0, 0);
      }
    }
  }
  #pragma unroll
  for (int n = 0; n < 4; ++n) {
    int col = n0 + n * 16 + m;
    float bv = bias[col];
    #pragma unroll
    for (int i = 0; i < 4; ++i) {
      int mrow = m0 + w * 16 + q * 4 + i;
      out[(size_t)mrow * N + col] = acc[n][i] + bv;
    }
  }
}

__global__ void k_tail(const u32* __restrict__ bufp, float* __restrict__ out) {
  int i = blockIdx.x * blockDim.x + threadIdx.x;
  if (i < NB * NH) out[i] = unpack_hl(bufp[(size_t)NT * NB * NH + i]);
}

// ---------------- launch ----------------

extern "C" void kernel_launch(void* const* d_in, const int* in_sizes, int n_in,
                              void* d_out, int out_size, void* d_ws, size_t ws_size,
                              hipStream_t stream) {
  const int*   tokens0    = (const int*)d_in[0];
  const int*   tokens1    = (const int*)d_in[1];
  const int*   conditions = (const int*)d_in[2];
  const float* hidden     = (const float*)d_in[3];
  const float* emb0       = (const float*)d_in[4];
  const float* emb1       = (const float*)d_in[5];
  const float* W_ih       = (const float*)d_in[6];
  const float* W_hh       = (const float*)d_in[7];
  const float* b_ih       = (const float*)d_in[8];
  const float* b_hh       = (const float*)d_in[9];
  const float* dec0_W     = (const float*)d_in[10];
  const float* dec0_b     = (const float*)d_in[11];
  const float* dec1_W     = (const float*)d_in[12];
  const float* dec1_b     = (const float*)d_in[13];

  char* wsb = (char*)d_ws;
  float* proj0 = (float*)wsb;                      // 12,582,912 B
  float* proj1 = (float*)(wsb + 12582912);         //  3,145,728 B
  float* Wt_ih = (float*)(wsb + 15728640);         //  3,145,728 B (reused below)
  // gdone/items/nitems/off_bp overlay Wt_ih's region: used AFTER k_proj
  int*   gdone   = (int*)(wsb + 15728640);         // 32*1026 ints = 131,328 B
  int*   items   = (int*)(wsb + 15859968);         // 32*1024 ints = 131,072 B
  int*   nitems  = (int*)(wsb + 15991040);         // 32 ints
  int*   off_bp  = (int*)(wsb + 15991168);         // 32*1025 ints = 131,200 B
  u32*   bufp  = (u32*)(wsb + 18874368);           // 1025*32*512 u32 = 67,174,400 B
  u16*   Wfh   = (u16*)(wsb + 86048768);           //  1,572,864 B
  u16*   Wfl   = (u16*)(wsb + 87621632);           //  1,572,864 B
  u16*   d0Wh  = (u16*)(wsb + 89194496);           //  2,097,152 B
  u16*   d0Wl  = (u16*)(wsb + 91291648);           //  2,097,152 B
  u16*   d1Wh  = (u16*)(wsb + 93388800);           //    524,288 B
  u16*   d1Wl  = (u16*)(wsb + 93913088);           //    524,288 B
  int*   iws   = (int*)(wsb + 94437376);
  int* plv       = iws;                    // 32768
  int* cntb      = iws + 32768;            // 32800
  int* node_list = iws + 65568;            // 32768

  float* out0 = (float*)d_out;
  float* out1 = out0 + (size_t)NB * NT * NV0;
  float* outT = out1 + (size_t)NB * NT * NV1;

  // Wt_ih produced+consumed first; then its region is reused for dataflow state.
  k_transpose<<<dim3(16, 48), dim3(32, 8), 0, stream>>>(W_ih, Wt_ih);
  k_proj<<<320, 256, 0, stream>>>(emb0, emb1, Wt_ih, proj0, proj1);
  k_init<<<130, 256, 0, stream>>>(hidden, bufp, gdone);
  k_wsplit<<<3072, 256, 0, stream>>>(W_hh, Wfh, Wfl);
  k_wsplit_dec<<<4096, 256, 0, stream>>>(dec0_W, d0Wh, d0Wl, NV0);
  k_wsplit_dec<<<1024, 256, 0, stream>>>(dec1_W, d1Wh, d1Wl, NV1);
  k_levels<<<32, 256, 0, stream>>>(conditions, plv, cntb);
  k_scan<<<1, 32, 0, stream>>>(cntb, items, nitems, off_bp);
  k_scatter<<<32, 256, 0, stream>>>(plv, off_bp, node_list);

  rnn_steps<<<NCHUNK * NB, 128, 0, stream>>>(items, nitems, node_list, conditions,
                                             tokens0, tokens1, Wfh, Wfl, proj0, proj1,
                                             b_ih, b_hh, bufp, gdone);

  k_dec<<<dim3(NV0 / 64, (NB * NT) / 64), 256, 0, stream>>>(bufp, d0Wh, d0Wl, dec0_b, out0, NV0);
  k_dec<<<dim3(NV1 / 64, (NB * NT) / 64), 256, 0, stream>>>(bufp, d1Wh, d1Wl, dec1_b, out1, NV1);
  k_tail<<<64, 256, 0, stream>>>(bufp, outT);
}